// Round 1
// baseline (378.345 us; speedup 1.0000x reference)
//
#include <hip/hip_runtime.h>
#include <hip/hip_bf16.h>

// GAT layer: B=4, N=2048, F=128, U=64, H=4, fp32 throughout.
// Pipeline:
//  k0: pack adj (64MB int32) -> bitmask (2MB)           [HBM-bound, ~12us]
//  k1: proj[h][b][n][u] = relu(x@W+b); s[h][b][n]       [~5us]
//  k2: per (h,b,itile,jchunk): w=adj?exp(si*sj):0 ; acc += w*proj ; Z+=w
//      (no max-subtraction: |s|<~4 so exp(s_i*s_j) can't overflow fp32;
//       softmax is shift-invariant so result is identical)
//  k3: out = 0.25 * sum_h (sum_jc P) / (sum_jc Z)
//
// d_ws layout (bytes):
//   proj     @ 0          : H*B*N*U f32 = 8,388,608 B
//   s        @ 8,388,608  : H*B*N   f32 =   131,072 B
//   adjbits  @ 8,519,680  : B*N*N/8     = 2,097,152 B
//   out_part @ 10,616,832 : H*JC*B*N*U f32 = 16,777,216 B
//   Z_part   @ 27,394,048 : H*JC*B*N f32 = 262,144 B
// total ~27.7 MB

#define Bdim 4
#define Ndim 2048
#define Fdim 128
#define Udim 64
#define Hdim 4
#define JC 2          // j-chunks per row
#define JCHUNK (Ndim / JC)
#define ITILE 128
#define JSUB 64

// ---------------- k0: pack adjacency to bitmask ----------------
__global__ __launch_bounds__(256) void pack_adj_kernel(
    const int* __restrict__ adj, unsigned long long* __restrict__ bits,
    int nchunks) {
  const int lane = threadIdx.x & 63;
  const int wid = (blockIdx.x * blockDim.x + threadIdx.x) >> 6;
  const int nw = (gridDim.x * blockDim.x) >> 6;
  for (int c = wid; c < nchunks; c += nw) {
    int v = adj[(size_t)c * 64 + lane];
    unsigned long long m = __ballot(v != 0);
    if (lane == 0) bits[c] = m;
  }
}

// ---------------- k1: projection + attention scalars ----------------
// grid: 512 blocks = (h:4, b:4, ntile:32), 256 threads.
// Each block: 64 rows x 64 u. Thread tile: 4 rows x 4 u.
__global__ __launch_bounds__(256) void proj_kernel(
    const float* __restrict__ x, const float* __restrict__ W,
    const float* __restrict__ bias, const float* __restrict__ a_w,
    const float* __restrict__ a_b, float* __restrict__ proj,
    float* __restrict__ s) {
  const int bid = blockIdx.x;
  const int nt = bid & 31;
  const int b = (bid >> 5) & 3;
  const int h = bid >> 7;
  const int n0 = nt * 64;

  __shared__ float Wl[Fdim][Udim];      // 32 KB
  __shared__ float xl[64][Fdim + 4];    // 33 KB, +4 pad keeps 16B align, kills bank conflicts
  __shared__ float bl[Udim];
  __shared__ float awl[Udim];
  __shared__ float sred[64][16];

  const int t = threadIdx.x;

  // load W[h] (128x64 f32, contiguous)
  const float* Wg = W + (size_t)h * Fdim * Udim;
  for (int k = t; k < Fdim * Udim / 4; k += 256) {
    ((float4*)&Wl[0][0])[k] = ((const float4*)Wg)[k];
  }
  if (t < Udim) {
    bl[t] = bias[h * Udim + t];
    awl[t] = a_w[h * Udim + t];
  }
  // load x tile (64 rows x 128 f)
  const float* xg = x + ((size_t)b * Ndim + n0) * Fdim;
  for (int k = t; k < 64 * Fdim / 4; k += 256) {
    int row = k >> 5;           // 32 float4 per row
    int c4 = k & 31;
    float4 v = ((const float4*)xg)[(size_t)row * (Fdim / 4) + c4];
    *(float4*)&xl[row][c4 * 4] = v;
  }
  __syncthreads();

  const int ug = t & 15, rg = t >> 4;
  const int u0 = ug * 4, r0 = rg * 4;
  float acc[4][4] = {};

#pragma unroll 4
  for (int f = 0; f < Fdim; ++f) {
    const float4 wv = *(const float4*)&Wl[f][u0];
    const float xv[4] = {xl[r0][f], xl[r0 + 1][f], xl[r0 + 2][f], xl[r0 + 3][f]};
#pragma unroll
    for (int c = 0; c < 4; ++c) {
      acc[c][0] = fmaf(xv[c], wv.x, acc[c][0]);
      acc[c][1] = fmaf(xv[c], wv.y, acc[c][1]);
      acc[c][2] = fmaf(xv[c], wv.z, acc[c][2]);
      acc[c][3] = fmaf(xv[c], wv.w, acc[c][3]);
    }
  }

  // bias + relu, store proj, compute s partials
  float* pg = proj + (((size_t)h * Bdim + b) * Ndim + n0) * Udim;
#pragma unroll
  for (int c = 0; c < 4; ++c) {
    float4 o;
    o.x = fmaxf(acc[c][0] + bl[u0 + 0], 0.f);
    o.y = fmaxf(acc[c][1] + bl[u0 + 1], 0.f);
    o.z = fmaxf(acc[c][2] + bl[u0 + 2], 0.f);
    o.w = fmaxf(acc[c][3] + bl[u0 + 3], 0.f);
    *(float4*)&pg[(size_t)(r0 + c) * Udim + u0] = o;
    float sp = o.x * awl[u0 + 0] + o.y * awl[u0 + 1] + o.z * awl[u0 + 2] +
               o.w * awl[u0 + 3];
    sred[r0 + c][ug] = sp;
  }
  __syncthreads();
  if (t < 64) {
    float sum = a_b[h];
#pragma unroll
    for (int k = 0; k < 16; ++k) sum += sred[t][k];
    s[((size_t)h * Bdim + b) * Ndim + n0 + t] = sum;
  }
}

// ---------------- k2: masked-softmax-weighted aggregation ----------------
// grid: 512 blocks = (h:4, b:4, itile:16, jc:2), 128 threads.
// Block: 128 i-rows x 1024 j x 64 u, per-thread 8i x 8u register tile.
__global__ __launch_bounds__(128) void attn_kernel(
    const float* __restrict__ proj, const float* __restrict__ s,
    const unsigned int* __restrict__ abits, float* __restrict__ out_part,
    float* __restrict__ Z_part) {
  const int bid = blockIdx.x;
  const int jc = bid & 1;
  const int it = (bid >> 1) & 15;
  const int b = (bid >> 5) & 3;
  const int h = bid >> 7;
  const int i0g = it * ITILE;
  const int j0g = jc * JCHUNK;

  __shared__ float s_j[JCHUNK];               // 4 KB
  __shared__ unsigned int ab[ITILE][32];      // 16 KB
  __shared__ float wl[JSUB][ITILE];           // 32 KB

  const int t = threadIdx.x;
  const size_t hb = (size_t)h * Bdim + b;
  const float* sg = s + hb * Ndim;

  for (int k = t; k < JCHUNK; k += 128) s_j[k] = sg[j0g + k];
  const float si = sg[i0g + t];  // thread t owns row i = t for w-compute
  for (int k = t; k < ITILE * 32; k += 128) {
    int i = k >> 5, w = k & 31;
    ab[i][w] = abits[((size_t)b * Ndim + i0g + i) * (Ndim / 32) + (j0g >> 5) + w];
  }

  float Zacc = 0.f;
  float acc[8][8] = {};
  const int ug = t & 7, ig = t >> 3;
  const int u0 = ug * 8, i0 = ig * 8;
  const float* projp = proj + (hb * Ndim + j0g) * Udim + u0;

  for (int js = 0; js < JCHUNK; js += JSUB) {
    __syncthreads();  // previous FMA phase done before overwriting wl
    const unsigned int word0 = ab[t][js >> 5];
    const unsigned int word1 = ab[t][(js >> 5) + 1];
#pragma unroll
    for (int jj = 0; jj < JSUB; ++jj) {
      const unsigned int wsel = (jj < 32) ? word0 : word1;
      float e = __expf(si * s_j[js + jj]);
      e = ((wsel >> (jj & 31)) & 1u) ? e : 0.f;
      wl[jj][t] = e;
      Zacc += e;
    }
    __syncthreads();
#pragma unroll 2
    for (int jj = 0; jj < JSUB; ++jj) {
      const float4 wA = *(const float4*)&wl[jj][i0];
      const float4 wB = *(const float4*)&wl[jj][i0 + 4];
      const float* pr = projp + (size_t)(js + jj) * Udim;
      const float4 pA = *(const float4*)pr;
      const float4 pB = *(const float4*)(pr + 4);
      const float wr[8] = {wA.x, wA.y, wA.z, wA.w, wB.x, wB.y, wB.z, wB.w};
      const float pc[8] = {pA.x, pA.y, pA.z, pA.w, pB.x, pB.y, pB.z, pB.w};
#pragma unroll
      for (int r = 0; r < 8; ++r)
#pragma unroll
        for (int c = 0; c < 8; ++c)
          acc[r][c] = fmaf(wr[r], pc[c], acc[r][c]);
    }
  }

  // write partials: out_part[h][jc][b][i][u], Z_part[h][jc][b][i]
  const size_t pslab = ((size_t)h * JC + jc) * Bdim + b;
  float* op = out_part + (pslab * Ndim + i0g + i0) * Udim + u0;
#pragma unroll
  for (int r = 0; r < 8; ++r) {
    float4 oA = {acc[r][0], acc[r][1], acc[r][2], acc[r][3]};
    float4 oB = {acc[r][4], acc[r][5], acc[r][6], acc[r][7]};
    *(float4*)&op[(size_t)r * Udim] = oA;
    *(float4*)&op[(size_t)r * Udim + 4] = oB;
  }
  Z_part[pslab * Ndim + i0g + t] = Zacc;
}

// ---------------- k3: combine partials, normalize, head-mean ----------------
__global__ __launch_bounds__(256) void combine_kernel(
    const float* __restrict__ out_part, const float* __restrict__ Z_part,
    float* __restrict__ out) {
  const int idx = blockIdx.x * 256 + threadIdx.x;  // 0..131071 (B*N*U/4)
  const int u4 = idx & 15;
  const size_t bn = (size_t)(idx >> 4);  // b*N+n in [0, 8192)
  float4 r = {0.f, 0.f, 0.f, 0.f};
#pragma unroll
  for (int h = 0; h < Hdim; ++h) {
    const size_t s0 = ((size_t)h * JC + 0) * (Bdim * Ndim) + bn;
    const size_t s1 = ((size_t)h * JC + 1) * (Bdim * Ndim) + bn;
    float4 p0 = ((const float4*)out_part)[s0 * (Udim / 4) + u4];
    float4 p1 = ((const float4*)out_part)[s1 * (Udim / 4) + u4];
    float z = Z_part[s0] + Z_part[s1];
    z = (z != 0.f) ? z : 1.f;
    const float inv = 1.f / z;
    r.x += (p0.x + p1.x) * inv;
    r.y += (p0.y + p1.y) * inv;
    r.z += (p0.z + p1.z) * inv;
    r.w += (p0.w + p1.w) * inv;
  }
  r.x *= 0.25f; r.y *= 0.25f; r.z *= 0.25f; r.w *= 0.25f;
  ((float4*)out)[idx] = r;
}

extern "C" void kernel_launch(void* const* d_in, const int* in_sizes, int n_in,
                              void* d_out, int out_size, void* d_ws,
                              size_t ws_size, hipStream_t stream) {
  const float* x = (const float*)d_in[0];
  const int* adj = (const int*)d_in[1];
  const float* W = (const float*)d_in[2];
  const float* bias = (const float*)d_in[3];
  const float* a_w = (const float*)d_in[4];
  const float* a_b = (const float*)d_in[5];
  float* out = (float*)d_out;

  char* ws = (char*)d_ws;
  float* proj = (float*)(ws + 0);
  float* s = (float*)(ws + 8388608);
  unsigned int* adjbits = (unsigned int*)(ws + 8519680);
  float* out_part = (float*)(ws + 10616832);
  float* Z_part = (float*)(ws + 27394048);

  const int nchunks = Bdim * Ndim * Ndim / 64;  // 262144
  pack_adj_kernel<<<1024, 256, 0, stream>>>(adj, (unsigned long long*)adjbits,
                                            nchunks);
  proj_kernel<<<Hdim * Bdim * 32, 256, 0, stream>>>(x, W, bias, a_w, a_b, proj,
                                                    s);
  attn_kernel<<<Hdim * Bdim * (Ndim / ITILE) * JC, 128, 0, stream>>>(
      proj, s, adjbits, out_part, Z_part);
  combine_kernel<<<(Bdim * Ndim * Udim / 4) / 256, 256, 0, stream>>>(
      out_part, Z_part, out);
}

// Round 2
// 265.383 us; speedup vs baseline: 1.4257x; 1.4257x over previous
//
#include <hip/hip_runtime.h>
#include <hip/hip_bf16.h>

// GAT layer: B=4, N=2048, F=128, U=64, H=4, fp32 throughout.
//  k0: pack adj (64MB int32) -> bitmask (2MB)
//  k1: proj[h][b][n][u] = relu(x@W+b); s[h][b][n]
//  k2: per (h,b,itile,jchunk): w=adj?exp(si*sj):0 ; acc += w*proj ; Z+=w
//      (no max-subtraction: |s|<~4 so exp(si*sj) <= ~1e7, fp32-safe; softmax
//       is shift-invariant so result is identical)
//  k3: out = 0.25 * sum_h (sum_jc P) / (sum_jc Z)
//
// d_ws layout (bytes), total ~27.7 MB (same as round-0 proven footprint):
//   proj     @ 0          : H*B*N*U f32 = 8,388,608
//   s        @ 8,388,608  : H*B*N   f32 =   131,072
//   adjbits  @ 8,519,680  : B*N*N/8     = 2,097,152
//   out_part @ 10,616,832 : H*JC*B*N*U f32 = 16,777,216
//   Z_part   @ 27,394,048 : H*JC*B*N f32 = 262,144

#define Bdim 4
#define Ndim 2048
#define Fdim 128
#define Udim 64
#define Hdim 4
#define JC 2
#define JCHUNK (Ndim / JC)   // 1024
#define ITILE 64
#define JSUB 64

// ---------------- k0: pack adjacency to bitmask ----------------
// 4 independent chunk loads per iteration to hide load->ballot latency.
__global__ __launch_bounds__(256) void pack_adj_kernel(
    const int* __restrict__ adj, unsigned long long* __restrict__ bits,
    int nchunks) {
  const int lane = threadIdx.x & 63;
  const int wid = (blockIdx.x * 256 + threadIdx.x) >> 6;
  const int nw = (gridDim.x * 256) >> 6;
  for (int c = wid * 4; c + 3 < nchunks; c += nw * 4) {
    int v0 = adj[(size_t)(c + 0) * 64 + lane];
    int v1 = adj[(size_t)(c + 1) * 64 + lane];
    int v2 = adj[(size_t)(c + 2) * 64 + lane];
    int v3 = adj[(size_t)(c + 3) * 64 + lane];
    unsigned long long m0 = __ballot(v0 != 0);
    unsigned long long m1 = __ballot(v1 != 0);
    unsigned long long m2 = __ballot(v2 != 0);
    unsigned long long m3 = __ballot(v3 != 0);
    if (lane == 0) {
      bits[c + 0] = m0;
      bits[c + 1] = m1;
      bits[c + 2] = m2;
      bits[c + 3] = m3;
    }
  }
}

// ---------------- k1: projection + attention scalars ----------------
// grid: 512 blocks = (h:4, b:4, ntile:32), 256 threads.
__global__ __launch_bounds__(256) void proj_kernel(
    const float* __restrict__ x, const float* __restrict__ W,
    const float* __restrict__ bias, const float* __restrict__ a_w,
    const float* __restrict__ a_b, float* __restrict__ proj,
    float* __restrict__ s) {
  const int bid = blockIdx.x;
  const int nt = bid & 31;
  const int b = (bid >> 5) & 3;
  const int h = bid >> 7;
  const int n0 = nt * 64;

  __shared__ float Wl[Fdim][Udim];
  __shared__ float xl[64][Fdim + 4];
  __shared__ float bl[Udim];
  __shared__ float awl[Udim];
  __shared__ float sred[64][16];

  const int t = threadIdx.x;

  const float* Wg = W + (size_t)h * Fdim * Udim;
  for (int k = t; k < Fdim * Udim / 4; k += 256) {
    ((float4*)&Wl[0][0])[k] = ((const float4*)Wg)[k];
  }
  if (t < Udim) {
    bl[t] = bias[h * Udim + t];
    awl[t] = a_w[h * Udim + t];
  }
  const float* xg = x + ((size_t)b * Ndim + n0) * Fdim;
  for (int k = t; k < 64 * Fdim / 4; k += 256) {
    int row = k >> 5;
    int c4 = k & 31;
    float4 v = ((const float4*)xg)[(size_t)row * (Fdim / 4) + c4];
    *(float4*)&xl[row][c4 * 4] = v;
  }
  __syncthreads();

  const int ug = t & 15, rg = t >> 4;
  const int u0 = ug * 4, r0 = rg * 4;
  float acc[4][4] = {};

#pragma unroll 4
  for (int f = 0; f < Fdim; ++f) {
    const float4 wv = *(const float4*)&Wl[f][u0];
    const float xv[4] = {xl[r0][f], xl[r0 + 1][f], xl[r0 + 2][f], xl[r0 + 3][f]};
#pragma unroll
    for (int c = 0; c < 4; ++c) {
      acc[c][0] = fmaf(xv[c], wv.x, acc[c][0]);
      acc[c][1] = fmaf(xv[c], wv.y, acc[c][1]);
      acc[c][2] = fmaf(xv[c], wv.z, acc[c][2]);
      acc[c][3] = fmaf(xv[c], wv.w, acc[c][3]);
    }
  }

  float* pg = proj + (((size_t)h * Bdim + b) * Ndim + n0) * Udim;
#pragma unroll
  for (int c = 0; c < 4; ++c) {
    float4 o;
    o.x = fmaxf(acc[c][0] + bl[u0 + 0], 0.f);
    o.y = fmaxf(acc[c][1] + bl[u0 + 1], 0.f);
    o.z = fmaxf(acc[c][2] + bl[u0 + 2], 0.f);
    o.w = fmaxf(acc[c][3] + bl[u0 + 3], 0.f);
    *(float4*)&pg[(size_t)(r0 + c) * Udim + u0] = o;
    float sp = o.x * awl[u0 + 0] + o.y * awl[u0 + 1] + o.z * awl[u0 + 2] +
               o.w * awl[u0 + 3];
    sred[r0 + c][ug] = sp;
  }
  __syncthreads();
  if (t < 64) {
    float sum = a_b[h];
#pragma unroll
    for (int k = 0; k < 16; ++k) sum += sred[t][k];
    s[((size_t)h * Bdim + b) * Ndim + n0 + t] = sum;
  }
}

// ---------------- k2: masked-softmax-weighted aggregation ----------------
// grid: 1024 blocks = (h:4, b:4, itile:32, jc:2), 256 threads (4 waves).
// Block: 64 i-rows x 1024 j x 64 u. Thread tile 4i x 4u.
// LDS ~29KB -> 4 blocks/CU (grid-limited) = 16 waves/CU.
__global__ __launch_bounds__(256, 4) void attn_kernel(
    const float* __restrict__ proj, const float* __restrict__ s,
    const unsigned int* __restrict__ abits, float* __restrict__ out_part,
    float* __restrict__ Z_part) {
  const int bid = blockIdx.x;
  const int jc = bid & 1;
  const int it = (bid >> 1) & 31;
  const int b = (bid >> 6) & 3;
  const int h = bid >> 8;
  const int i0g = it * ITILE;
  const int j0g = jc * JCHUNK;

  __shared__ float s_j[JCHUNK];                     // 4 KB
  __shared__ unsigned int ab[ITILE][JCHUNK / 32];   // 8 KB
  __shared__ float wl[JSUB][ITILE];                 // 16 KB
  __shared__ float zred[ITILE][4];                  // 1 KB

  const int t = threadIdx.x;
  const size_t hb = (size_t)h * Bdim + b;
  const float* sg = s + hb * Ndim;

  for (int k = t; k < JCHUNK; k += 256) s_j[k] = sg[j0g + k];
  const int irow = t & 63, jq = t >> 6;
  const float si = sg[i0g + irow];
  for (int k = t; k < ITILE * (JCHUNK / 32); k += 256) {
    int i = k >> 5, w = k & 31;
    ab[i][w] =
        abits[((size_t)b * Ndim + i0g + i) * (Ndim / 32) + (j0g >> 5) + w];
  }

  float Zacc = 0.f;
  float acc[4][4] = {};
  const int ug = t & 15, ig = t >> 4;
  const int u0 = ug * 4, i0 = ig * 4;
  const float* projp = proj + (hb * Ndim + j0g) * Udim;
  __syncthreads();

  for (int js = 0; js < JCHUNK; js += JSUB) {
    // ---- w-compute: 256 threads cover the 64x64 w-tile (16 exps each) ----
    const unsigned int word = ab[irow][(js >> 5) + (jq >> 1)];
    const unsigned int half = word >> ((jq & 1) * 16);
#pragma unroll
    for (int k = 0; k < 16; ++k) {
      float e = __expf(si * s_j[js + jq * 16 + k]);
      e = ((half >> k) & 1u) ? e : 0.f;
      wl[jq * 16 + k][irow] = e;
      Zacc += e;
    }
    __syncthreads();
    // ---- FMA: thread tile 4i x 4u; wl reads bank-conflict-free ----
#pragma unroll 4
    for (int jj = 0; jj < JSUB; ++jj) {
      const float4 wv = *(const float4*)&wl[jj][i0];
      const float4 pv = *(const float4*)&projp[(size_t)(js + jj) * Udim + u0];
      acc[0][0] = fmaf(wv.x, pv.x, acc[0][0]);
      acc[0][1] = fmaf(wv.x, pv.y, acc[0][1]);
      acc[0][2] = fmaf(wv.x, pv.z, acc[0][2]);
      acc[0][3] = fmaf(wv.x, pv.w, acc[0][3]);
      acc[1][0] = fmaf(wv.y, pv.x, acc[1][0]);
      acc[1][1] = fmaf(wv.y, pv.y, acc[1][1]);
      acc[1][2] = fmaf(wv.y, pv.z, acc[1][2]);
      acc[1][3] = fmaf(wv.y, pv.w, acc[1][3]);
      acc[2][0] = fmaf(wv.z, pv.x, acc[2][0]);
      acc[2][1] = fmaf(wv.z, pv.y, acc[2][1]);
      acc[2][2] = fmaf(wv.z, pv.z, acc[2][2]);
      acc[2][3] = fmaf(wv.z, pv.w, acc[2][3]);
      acc[3][0] = fmaf(wv.w, pv.x, acc[3][0]);
      acc[3][1] = fmaf(wv.w, pv.y, acc[3][1]);
      acc[3][2] = fmaf(wv.w, pv.z, acc[3][2]);
      acc[3][3] = fmaf(wv.w, pv.w, acc[3][3]);
    }
    __syncthreads();
  }

  // write partials: out_part[h][jc][b][i][u], Z_part[h][jc][b][i]
  const size_t pslab = ((size_t)h * JC + jc) * Bdim + b;
  float* op = out_part + (pslab * Ndim + i0g + i0) * Udim + u0;
#pragma unroll
  for (int r = 0; r < 4; ++r) {
    float4 o = {acc[r][0], acc[r][1], acc[r][2], acc[r][3]};
    *(float4*)&op[(size_t)r * Udim] = o;
  }
  zred[irow][jq] = Zacc;
  __syncthreads();
  if (t < ITILE) {
    float z = zred[t][0] + zred[t][1] + zred[t][2] + zred[t][3];
    Z_part[pslab * Ndim + i0g + t] = z;
  }
}

// ---------------- k3: combine partials, normalize, head-mean ----------------
__global__ __launch_bounds__(256) void combine_kernel(
    const float* __restrict__ out_part, const float* __restrict__ Z_part,
    float* __restrict__ out) {
  const int idx = blockIdx.x * 256 + threadIdx.x;
  const int u4 = idx & 15;
  const size_t bn = (size_t)(idx >> 4);
  float4 r = {0.f, 0.f, 0.f, 0.f};
#pragma unroll
  for (int h = 0; h < Hdim; ++h) {
    const size_t s0 = ((size_t)h * JC + 0) * (Bdim * Ndim) + bn;
    const size_t s1 = ((size_t)h * JC + 1) * (Bdim * Ndim) + bn;
    float4 p0 = ((const float4*)out_part)[s0 * (Udim / 4) + u4];
    float4 p1 = ((const float4*)out_part)[s1 * (Udim / 4) + u4];
    float z = Z_part[s0] + Z_part[s1];
    z = (z != 0.f) ? z : 1.f;
    const float inv = 1.f / z;
    r.x += (p0.x + p1.x) * inv;
    r.y += (p0.y + p1.y) * inv;
    r.z += (p0.z + p1.z) * inv;
    r.w += (p0.w + p1.w) * inv;
  }
  r.x *= 0.25f; r.y *= 0.25f; r.z *= 0.25f; r.w *= 0.25f;
  ((float4*)out)[idx] = r;
}

extern "C" void kernel_launch(void* const* d_in, const int* in_sizes, int n_in,
                              void* d_out, int out_size, void* d_ws,
                              size_t ws_size, hipStream_t stream) {
  const float* x = (const float*)d_in[0];
  const int* adj = (const int*)d_in[1];
  const float* W = (const float*)d_in[2];
  const float* bias = (const float*)d_in[3];
  const float* a_w = (const float*)d_in[4];
  const float* a_b = (const float*)d_in[5];
  float* out = (float*)d_out;

  char* ws = (char*)d_ws;
  float* proj = (float*)(ws + 0);
  float* s = (float*)(ws + 8388608);
  unsigned int* adjbits = (unsigned int*)(ws + 8519680);
  float* out_part = (float*)(ws + 10616832);
  float* Z_part = (float*)(ws + 27394048);

  const int nchunks = Bdim * Ndim * Ndim / 64;  // 262144
  pack_adj_kernel<<<2048, 256, 0, stream>>>(adj, (unsigned long long*)adjbits,
                                            nchunks);
  proj_kernel<<<Hdim * Bdim * 32, 256, 0, stream>>>(x, W, bias, a_w, a_b, proj,
                                                    s);
  attn_kernel<<<Hdim * Bdim * (Ndim / ITILE) * JC, 256, 0, stream>>>(
      proj, s, adjbits, out_part, Z_part);
  combine_kernel<<<(Bdim * Ndim * Udim / 4) / 256, 256, 0, stream>>>(
      out_part, Z_part, out);
}

// Round 3
// 242.230 us; speedup vs baseline: 1.5619x; 1.0956x over previous
//
#include <hip/hip_runtime.h>
#include <hip/hip_bf16.h>

// GAT layer: B=4, N=2048, F=128, U=64, H=4.
//  k0: pack adj (64MB int32) -> bitmask (2MB)
//  k1: proj GEMM (vector fp32) -> pT_hi/pT_lo bf16 [h][b][u][n] (split fp32),
//      plus s[h][b][n] f32
//  k2: MFMA attention: w=adj?exp(si*sj):0 computed in-register, split to
//      bf16 hi/lo; out += w@p via 3-product split-bf16 MFMA (err ~2^-17).
//      A/B fragment k-mapping chosen freely (permutation-invariant over k;
//      A,B mappings symmetric on CDNA), D layout per verified m89.
//  k3: combine: out = 0.25 * sum_h (P0+P1)/(Z0+Z1)
//
// d_ws layout (bytes):
//   pT_hi    @ 0          : H*B*U*N bf16 = 4,194,304
//   pT_lo    @ 4,194,304  : H*B*U*N bf16 = 4,194,304
//   s        @ 8,388,608  : H*B*N   f32  =   131,072
//   adjbits  @ 8,519,680  : B*N*N/8      = 2,097,152
//   out_part @ 10,616,832 : H*JC*B*N*U f32 = 16,777,216
//   Z_part   @ 27,394,048 : H*JC*B*N f32 = 262,144

#define Bdim 4
#define Ndim 2048
#define Fdim 128
#define Udim 64
#define Hdim 4
#define JC 2
#define JCHUNK (Ndim / JC)  // 1024

typedef __attribute__((ext_vector_type(8))) short short8;
typedef __attribute__((ext_vector_type(4))) short short4v;
typedef __attribute__((ext_vector_type(4))) float f32x4;

__device__ inline unsigned short f2bf_u(float f) {
  union { float f; unsigned u; } v;
  v.f = f;
  unsigned r = v.u + 0x7FFFu + ((v.u >> 16) & 1u);  // RNE (finite inputs only)
  return (unsigned short)(r >> 16);
}
__device__ inline float bf2f(unsigned short s) {
  union { float f; unsigned u; } v;
  v.u = ((unsigned)s) << 16;
  return v.f;
}

// ---------------- k0: pack adjacency to bitmask ----------------
__global__ __launch_bounds__(256) void pack_adj_kernel(
    const int* __restrict__ adj, unsigned long long* __restrict__ bits,
    int nchunks) {
  const int lane = threadIdx.x & 63;
  const int wid = (blockIdx.x * 256 + threadIdx.x) >> 6;
  const int nw = (gridDim.x * 256) >> 6;
  for (int c = wid * 4; c + 3 < nchunks; c += nw * 4) {
    int v0 = adj[(size_t)(c + 0) * 64 + lane];
    int v1 = adj[(size_t)(c + 1) * 64 + lane];
    int v2 = adj[(size_t)(c + 2) * 64 + lane];
    int v3 = adj[(size_t)(c + 3) * 64 + lane];
    unsigned long long m0 = __ballot(v0 != 0);
    unsigned long long m1 = __ballot(v1 != 0);
    unsigned long long m2 = __ballot(v2 != 0);
    unsigned long long m3 = __ballot(v3 != 0);
    if (lane == 0) {
      bits[c + 0] = m0;
      bits[c + 1] = m1;
      bits[c + 2] = m2;
      bits[c + 3] = m3;
    }
  }
}

// ---------------- k1: projection -> split-bf16 transposed + s ----------------
// grid: 512 blocks = (h:4, b:4, ntile:32), 256 threads. 64 rows x 64 u each.
__global__ __launch_bounds__(256) void proj_kernel(
    const float* __restrict__ x, const float* __restrict__ W,
    const float* __restrict__ bias, const float* __restrict__ a_w,
    const float* __restrict__ a_b, unsigned short* __restrict__ pTh,
    unsigned short* __restrict__ pTl, float* __restrict__ s) {
  const int bid = blockIdx.x;
  const int nt = bid & 31;
  const int b = (bid >> 5) & 3;
  const int h = bid >> 7;
  const int n0 = nt * 64;

  __shared__ float Wl[Fdim][Udim];
  __shared__ float xl[64][Fdim + 4];
  __shared__ float bl[Udim];
  __shared__ float awl[Udim];
  __shared__ float sred[64][16];

  const int t = threadIdx.x;

  const float* Wg = W + (size_t)h * Fdim * Udim;
  for (int k = t; k < Fdim * Udim / 4; k += 256) {
    ((float4*)&Wl[0][0])[k] = ((const float4*)Wg)[k];
  }
  if (t < Udim) {
    bl[t] = bias[h * Udim + t];
    awl[t] = a_w[h * Udim + t];
  }
  const float* xg = x + ((size_t)b * Ndim + n0) * Fdim;
  for (int k = t; k < 64 * Fdim / 4; k += 256) {
    int row = k >> 5;
    int c4 = k & 31;
    float4 v = ((const float4*)xg)[(size_t)row * (Fdim / 4) + c4];
    *(float4*)&xl[row][c4 * 4] = v;
  }
  __syncthreads();

  const int ug = t & 15, rg = t >> 4;
  const int u0 = ug * 4, r0 = rg * 4;
  float acc[4][4] = {};

#pragma unroll 4
  for (int f = 0; f < Fdim; ++f) {
    const float4 wv = *(const float4*)&Wl[f][u0];
    const float xv[4] = {xl[r0][f], xl[r0 + 1][f], xl[r0 + 2][f], xl[r0 + 3][f]};
#pragma unroll
    for (int c = 0; c < 4; ++c) {
      acc[c][0] = fmaf(xv[c], wv.x, acc[c][0]);
      acc[c][1] = fmaf(xv[c], wv.y, acc[c][1]);
      acc[c][2] = fmaf(xv[c], wv.z, acc[c][2]);
      acc[c][3] = fmaf(xv[c], wv.w, acc[c][3]);
    }
  }

  float po[4][4];
#pragma unroll
  for (int c = 0; c < 4; ++c)
#pragma unroll
    for (int k = 0; k < 4; ++k)
      po[c][k] = fmaxf(acc[c][k] + bl[u0 + k], 0.f);

  const size_t hb = (size_t)h * Bdim + b;
  unsigned short* ph = pTh + hb * (size_t)(Udim * Ndim);
  unsigned short* pl = pTl + hb * (size_t)(Udim * Ndim);
#pragma unroll
  for (int k = 0; k < 4; ++k) {
    short4v hi4, lo4;
#pragma unroll
    for (int c = 0; c < 4; ++c) {
      unsigned short hh = f2bf_u(po[c][k]);
      hi4[c] = (short)hh;
      lo4[c] = (short)f2bf_u(po[c][k] - bf2f(hh));
    }
    *(short4v*)(ph + (size_t)(u0 + k) * Ndim + n0 + r0) = hi4;
    *(short4v*)(pl + (size_t)(u0 + k) * Ndim + n0 + r0) = lo4;
  }

#pragma unroll
  for (int c = 0; c < 4; ++c) {
    float sp = po[c][0] * awl[u0 + 0] + po[c][1] * awl[u0 + 1] +
               po[c][2] * awl[u0 + 2] + po[c][3] * awl[u0 + 3];
    sred[r0 + c][ug] = sp;
  }
  __syncthreads();
  if (t < 64) {
    float sum = a_b[h];
#pragma unroll
    for (int k = 0; k < 16; ++k) sum += sred[t][k];
    s[hb * Ndim + n0 + t] = sum;
  }
}

// ---------------- k2: MFMA masked-softmax aggregation ----------------
// grid: 1024 blocks = (h:4, b:4, itile:32, jc:2), 256 threads (4 waves).
// Wave wv owns i-rows [i0g+wv*16, +16), all 64 u, JCHUNK j.
// A-frag: lane(q,li) row=li, k=q*8+e (own-chosen bijection, same for B).
// B-frag: lane(q,li) col(u)=li, k=q*8+e -> pT[u][j0+q*8+e] = 16B short8 load.
// D (verified m89): col=lane&15, row=(lane>>4)*4+reg.
__global__ __launch_bounds__(256, 4) void attn_mfma_kernel(
    const unsigned short* __restrict__ pTh,
    const unsigned short* __restrict__ pTl, const float* __restrict__ s,
    const unsigned int* __restrict__ abits, float* __restrict__ out_part,
    float* __restrict__ Z_part) {
  const int bid = blockIdx.x;
  const int jc = bid & 1;
  const int it = (bid >> 1) & 31;
  const int b = (bid >> 6) & 3;
  const int h = bid >> 8;
  const int i0g = it * 64;
  const int j0g = jc * JCHUNK;

  __shared__ float sj[JCHUNK];         // 4 KB
  __shared__ unsigned int ab[64][33];  // 8.25 KB, padded: bank=(i+w)%32
  __shared__ float zl[4][4][16];       // 1 KB

  const int t = threadIdx.x;
  const int wv = t >> 6;
  const int lane = t & 63;
  const int q = lane >> 4;
  const int li = lane & 15;
  const size_t hb = (size_t)h * Bdim + b;
  const float* sg = s + hb * Ndim;

  for (int k = t; k < JCHUNK; k += 256) sj[k] = sg[j0g + k];
  for (int k = t; k < 64 * 32; k += 256) {
    int row = k >> 5, w = k & 31;
    ab[row][w] =
        abits[((size_t)b * Ndim + i0g + row) * (Ndim / 32) + (j0g >> 5) + w];
  }
  const int irow = wv * 16 + li;
  const float si = sg[i0g + irow];

  const unsigned short* bh =
      pTh + hb * (size_t)(Udim * Ndim) + (size_t)li * Ndim + j0g + q * 8;
  const unsigned short* bl2 =
      pTl + hb * (size_t)(Udim * Ndim) + (size_t)li * Ndim + j0g + q * 8;

  f32x4 acc[4] = {};
  float zacc = 0.f;
  __syncthreads();

  for (int js = 0; js < JCHUNK; js += 32) {
    // ---- A production: 8 masked exps in registers ----
    const unsigned int mb = (ab[irow][js >> 5] >> (q * 8)) & 0xffu;
    const f32x4 s0 = *(const f32x4*)&sj[js + q * 8];
    const f32x4 s1 = *(const f32x4*)&sj[js + q * 8 + 4];
    const float sv[8] = {s0.x, s0.y, s0.z, s0.w, s1.x, s1.y, s1.z, s1.w};
    short8 ahi, alo;
#pragma unroll
    for (int e = 0; e < 8; ++e) {
      float we = __expf(si * sv[e]);
      we = ((mb >> e) & 1u) ? we : 0.f;
      zacc += we;
      unsigned short hh = f2bf_u(we);
      ahi[e] = (short)hh;
      alo[e] = (short)f2bf_u(we - bf2f(hh));
    }
    // ---- B loads: 16B per lane per (u-tile, hi/lo) ----
    const short8 b0h = *(const short8*)(bh + 0 * 16 * Ndim + js);
    const short8 b1h = *(const short8*)(bh + 1 * 16 * Ndim + js);
    const short8 b2h = *(const short8*)(bh + 2 * 16 * Ndim + js);
    const short8 b3h = *(const short8*)(bh + 3 * 16 * Ndim + js);
    const short8 b0l = *(const short8*)(bl2 + 0 * 16 * Ndim + js);
    const short8 b1l = *(const short8*)(bl2 + 1 * 16 * Ndim + js);
    const short8 b2l = *(const short8*)(bl2 + 2 * 16 * Ndim + js);
    const short8 b3l = *(const short8*)(bl2 + 3 * 16 * Ndim + js);
    // ---- 3-product split-bf16 MFMA ----
    acc[0] = __builtin_amdgcn_mfma_f32_16x16x32_bf16(ahi, b0h, acc[0], 0, 0, 0);
    acc[1] = __builtin_amdgcn_mfma_f32_16x16x32_bf16(ahi, b1h, acc[1], 0, 0, 0);
    acc[2] = __builtin_amdgcn_mfma_f32_16x16x32_bf16(ahi, b2h, acc[2], 0, 0, 0);
    acc[3] = __builtin_amdgcn_mfma_f32_16x16x32_bf16(ahi, b3h, acc[3], 0, 0, 0);
    acc[0] = __builtin_amdgcn_mfma_f32_16x16x32_bf16(alo, b0h, acc[0], 0, 0, 0);
    acc[1] = __builtin_amdgcn_mfma_f32_16x16x32_bf16(alo, b1h, acc[1], 0, 0, 0);
    acc[2] = __builtin_amdgcn_mfma_f32_16x16x32_bf16(alo, b2h, acc[2], 0, 0, 0);
    acc[3] = __builtin_amdgcn_mfma_f32_16x16x32_bf16(alo, b3h, acc[3], 0, 0, 0);
    acc[0] = __builtin_amdgcn_mfma_f32_16x16x32_bf16(ahi, b0l, acc[0], 0, 0, 0);
    acc[1] = __builtin_amdgcn_mfma_f32_16x16x32_bf16(ahi, b1l, acc[1], 0, 0, 0);
    acc[2] = __builtin_amdgcn_mfma_f32_16x16x32_bf16(ahi, b2l, acc[2], 0, 0, 0);
    acc[3] = __builtin_amdgcn_mfma_f32_16x16x32_bf16(ahi, b3l, acc[3], 0, 0, 0);
  }

  zl[wv][q][li] = zacc;
  __syncthreads();

  const size_t pslab = ((size_t)h * JC + jc) * Bdim + b;
  if (q == 0) {
    float z = zl[wv][0][li] + zl[wv][1][li] + zl[wv][2][li] + zl[wv][3][li];
    Z_part[pslab * Ndim + i0g + wv * 16 + li] = z;
  }
  float* op = out_part + (pslab * Ndim + i0g + wv * 16) * Udim;
#pragma unroll
  for (int r = 0; r < 4; ++r) {
    const int ir = q * 4 + r;
#pragma unroll
    for (int m = 0; m < 4; ++m) {
      op[(size_t)ir * Udim + m * 16 + li] = acc[m][r];
    }
  }
}

// ---------------- k3: combine partials, normalize, head-mean ----------------
__global__ __launch_bounds__(256) void combine_kernel(
    const float* __restrict__ out_part, const float* __restrict__ Z_part,
    float* __restrict__ out) {
  const int idx = blockIdx.x * 256 + threadIdx.x;
  const int u4 = idx & 15;
  const size_t bn = (size_t)(idx >> 4);
  float4 r = {0.f, 0.f, 0.f, 0.f};
#pragma unroll
  for (int h = 0; h < Hdim; ++h) {
    const size_t s0 = ((size_t)h * JC + 0) * (Bdim * Ndim) + bn;
    const size_t s1 = ((size_t)h * JC + 1) * (Bdim * Ndim) + bn;
    float4 p0 = ((const float4*)out_part)[s0 * (Udim / 4) + u4];
    float4 p1 = ((const float4*)out_part)[s1 * (Udim / 4) + u4];
    float z = Z_part[s0] + Z_part[s1];
    z = (z != 0.f) ? z : 1.f;
    const float inv = 1.f / z;
    r.x += (p0.x + p1.x) * inv;
    r.y += (p0.y + p1.y) * inv;
    r.z += (p0.z + p1.z) * inv;
    r.w += (p0.w + p1.w) * inv;
  }
  r.x *= 0.25f; r.y *= 0.25f; r.z *= 0.25f; r.w *= 0.25f;
  ((float4*)out)[idx] = r;
}

extern "C" void kernel_launch(void* const* d_in, const int* in_sizes, int n_in,
                              void* d_out, int out_size, void* d_ws,
                              size_t ws_size, hipStream_t stream) {
  const float* x = (const float*)d_in[0];
  const int* adj = (const int*)d_in[1];
  const float* W = (const float*)d_in[2];
  const float* bias = (const float*)d_in[3];
  const float* a_w = (const float*)d_in[4];
  const float* a_b = (const float*)d_in[5];
  float* out = (float*)d_out;

  char* ws = (char*)d_ws;
  unsigned short* pTh = (unsigned short*)(ws + 0);
  unsigned short* pTl = (unsigned short*)(ws + 4194304);
  float* s = (float*)(ws + 8388608);
  unsigned int* adjbits = (unsigned int*)(ws + 8519680);
  float* out_part = (float*)(ws + 10616832);
  float* Z_part = (float*)(ws + 27394048);

  const int nchunks = Bdim * Ndim * Ndim / 64;  // 262144
  pack_adj_kernel<<<2048, 256, 0, stream>>>(adj, (unsigned long long*)adjbits,
                                            nchunks);
  proj_kernel<<<Hdim * Bdim * 32, 256, 0, stream>>>(x, W, bias, a_w, a_b, pTh,
                                                    pTl, s);
  attn_mfma_kernel<<<Hdim * Bdim * 32 * JC, 256, 0, stream>>>(
      pTh, pTl, s, adjbits, out_part, Z_part);
  combine_kernel<<<(Bdim * Ndim * Udim / 4) / 256, 256, 0, stream>>>(
      out_part, Z_part, out);
}

// Round 4
// 169.821 us; speedup vs baseline: 2.2279x; 1.4264x over previous
//
#include <hip/hip_runtime.h>
#include <hip/hip_bf16.h>

// GAT layer: B=4, N=2048, F=128, U=64, H=4.
//  k0: pack adj (64MB int32) -> bitmask (2MB)
//  k1: proj GEMM (vector fp32) -> pT_hi/pT_lo bf16 [h][b][u][n] (split fp32),
//      plus s[h][b][n] f32
//  k2: MFMA attention, LDS-staged B (double-buffered global_load_lds,
//      fragment-linear layout), w=adj?exp(si*sj):0 in-register, split bf16;
//      3-product split-bf16 MFMA (err ~2^-17). D layout per verified m89.
//  k3: combine: out = 0.25 * sum_h (P0+P1)/(Z0+Z1)
//
// d_ws layout (bytes):
//   pT_hi    @ 0          : H*B*U*N bf16 = 4,194,304
//   pT_lo    @ 4,194,304  : H*B*U*N bf16 = 4,194,304
//   s        @ 8,388,608  : H*B*N   f32  =   131,072
//   adjbits  @ 8,519,680  : B*N*N/8      = 2,097,152
//   out_part @ 10,616,832 : H*JC*B*N*U f32 = 16,777,216
//   Z_part   @ 27,394,048 : H*JC*B*N f32 = 262,144

#define Bdim 4
#define Ndim 2048
#define Fdim 128
#define Udim 64
#define Hdim 4
#define JC 2
#define JCHUNK (Ndim / JC)  // 1024

typedef __attribute__((ext_vector_type(8))) short short8;
typedef __attribute__((ext_vector_type(4))) short short4v;
typedef __attribute__((ext_vector_type(4))) float f32x4;

__device__ inline unsigned short f2bf_u(float f) {
  union { float f; unsigned u; } v;
  v.f = f;
  unsigned r = v.u + 0x7FFFu + ((v.u >> 16) & 1u);  // RNE (finite inputs only)
  return (unsigned short)(r >> 16);
}
__device__ inline float bf2f(unsigned short s) {
  union { float f; unsigned u; } v;
  v.u = ((unsigned)s) << 16;
  return v.f;
}

// async global->LDS, 16B per lane; dest = wave-uniform base + lane*16
__device__ __forceinline__ void stage16(const void* g, void* l) {
  __builtin_amdgcn_global_load_lds(
      (const __attribute__((address_space(1))) unsigned int*)g,
      (__attribute__((address_space(3))) unsigned int*)l, 16, 0, 0);
}

// ---------------- k0: pack adjacency to bitmask ----------------
__global__ __launch_bounds__(256) void pack_adj_kernel(
    const int* __restrict__ adj, unsigned long long* __restrict__ bits,
    int nchunks) {
  const int lane = threadIdx.x & 63;
  const int wid = (blockIdx.x * 256 + threadIdx.x) >> 6;
  const int nw = (gridDim.x * 256) >> 6;
  for (int c = wid * 4; c + 3 < nchunks; c += nw * 4) {
    int v0 = adj[(size_t)(c + 0) * 64 + lane];
    int v1 = adj[(size_t)(c + 1) * 64 + lane];
    int v2 = adj[(size_t)(c + 2) * 64 + lane];
    int v3 = adj[(size_t)(c + 3) * 64 + lane];
    unsigned long long m0 = __ballot(v0 != 0);
    unsigned long long m1 = __ballot(v1 != 0);
    unsigned long long m2 = __ballot(v2 != 0);
    unsigned long long m3 = __ballot(v3 != 0);
    if (lane == 0) {
      bits[c + 0] = m0;
      bits[c + 1] = m1;
      bits[c + 2] = m2;
      bits[c + 3] = m3;
    }
  }
}

// ---------------- k1: projection -> split-bf16 transposed + s ----------------
__global__ __launch_bounds__(256) void proj_kernel(
    const float* __restrict__ x, const float* __restrict__ W,
    const float* __restrict__ bias, const float* __restrict__ a_w,
    const float* __restrict__ a_b, unsigned short* __restrict__ pTh,
    unsigned short* __restrict__ pTl, float* __restrict__ s) {
  const int bid = blockIdx.x;
  const int nt = bid & 31;
  const int b = (bid >> 5) & 3;
  const int h = bid >> 7;
  const int n0 = nt * 64;

  __shared__ float Wl[Fdim][Udim];
  __shared__ float xl[64][Fdim + 4];
  __shared__ float bl[Udim];
  __shared__ float awl[Udim];
  __shared__ float sred[64][16];

  const int t = threadIdx.x;

  const float* Wg = W + (size_t)h * Fdim * Udim;
  for (int k = t; k < Fdim * Udim / 4; k += 256) {
    ((float4*)&Wl[0][0])[k] = ((const float4*)Wg)[k];
  }
  if (t < Udim) {
    bl[t] = bias[h * Udim + t];
    awl[t] = a_w[h * Udim + t];
  }
  const float* xg = x + ((size_t)b * Ndim + n0) * Fdim;
  for (int k = t; k < 64 * Fdim / 4; k += 256) {
    int row = k >> 5;
    int c4 = k & 31;
    float4 v = ((const float4*)xg)[(size_t)row * (Fdim / 4) + c4];
    *(float4*)&xl[row][c4 * 4] = v;
  }
  __syncthreads();

  const int ug = t & 15, rg = t >> 4;
  const int u0 = ug * 4, r0 = rg * 4;
  float acc[4][4] = {};

#pragma unroll 4
  for (int f = 0; f < Fdim; ++f) {
    const float4 wv = *(const float4*)&Wl[f][u0];
    const float xv[4] = {xl[r0][f], xl[r0 + 1][f], xl[r0 + 2][f], xl[r0 + 3][f]};
#pragma unroll
    for (int c = 0; c < 4; ++c) {
      acc[c][0] = fmaf(xv[c], wv.x, acc[c][0]);
      acc[c][1] = fmaf(xv[c], wv.y, acc[c][1]);
      acc[c][2] = fmaf(xv[c], wv.z, acc[c][2]);
      acc[c][3] = fmaf(xv[c], wv.w, acc[c][3]);
    }
  }

  float po[4][4];
#pragma unroll
  for (int c = 0; c < 4; ++c)
#pragma unroll
    for (int k = 0; k < 4; ++k)
      po[c][k] = fmaxf(acc[c][k] + bl[u0 + k], 0.f);

  const size_t hb = (size_t)h * Bdim + b;
  unsigned short* ph = pTh + hb * (size_t)(Udim * Ndim);
  unsigned short* pl = pTl + hb * (size_t)(Udim * Ndim);
#pragma unroll
  for (int k = 0; k < 4; ++k) {
    short4v hi4, lo4;
#pragma unroll
    for (int c = 0; c < 4; ++c) {
      unsigned short hh = f2bf_u(po[c][k]);
      hi4[c] = (short)hh;
      lo4[c] = (short)f2bf_u(po[c][k] - bf2f(hh));
    }
    *(short4v*)(ph + (size_t)(u0 + k) * Ndim + n0 + r0) = hi4;
    *(short4v*)(pl + (size_t)(u0 + k) * Ndim + n0 + r0) = lo4;
  }

#pragma unroll
  for (int c = 0; c < 4; ++c) {
    float sp = po[c][0] * awl[u0 + 0] + po[c][1] * awl[u0 + 1] +
               po[c][2] * awl[u0 + 2] + po[c][3] * awl[u0 + 3];
    sred[r0 + c][ug] = sp;
  }
  __syncthreads();
  if (t < 64) {
    float sum = a_b[h];
#pragma unroll
    for (int k = 0; k < 16; ++k) sum += sred[t][k];
    s[hb * Ndim + n0 + t] = sum;
  }
}

// ---------------- k2: MFMA masked-softmax aggregation, LDS-staged B --------
// grid: 1024 blocks = (h:4, b:4, itile:32, jc:2), 256 threads (4 waves).
// Wave wv owns i-rows [i0g+wv*16,+16). Per 32-j step:
//   - wave wv stages u-tile m=wv (hi+lo) for the NEXT step via
//     global_load_lds (per-lane global addr, linear LDS dest = frag order)
//   - A-frag (w weights) computed in-register: 8 masked exps + hi/lo split
//   - 8 ds_read_b128 (4 u-tiles x hi/lo), 12 MFMA (3-product split-bf16)
//   - one __syncthreads() per step (drains vmcnt -> staged data ready)
__global__ __launch_bounds__(256, 4) void attn_mfma_kernel(
    const unsigned short* __restrict__ pTh,
    const unsigned short* __restrict__ pTl, const float* __restrict__ s,
    const unsigned int* __restrict__ abits, float* __restrict__ out_part,
    float* __restrict__ Z_part) {
  const int bid = blockIdx.x;
  const int jc = bid & 1;
  const int it = (bid >> 1) & 31;
  const int b = (bid >> 6) & 3;
  const int h = bid >> 8;
  const int i0g = it * 64;
  const int j0g = jc * JCHUNK;

  __shared__ float sj[JCHUNK];         // 4 KB
  __shared__ unsigned int ab[64][33];  // 8.25 KB padded
  __shared__ short Bst[2][8][512];     // 16 KB: [buf][m*2+hl][lane*8]
  __shared__ float zl[4][4][16];       // 1 KB

  const int t = threadIdx.x;
  const int wv = t >> 6;
  const int lane = t & 63;
  const int q = lane >> 4;
  const int li = lane & 15;
  const size_t hb = (size_t)h * Bdim + b;
  const float* sg = s + hb * Ndim;

  // prologue loads
  ((float4*)sj)[t] = ((const float4*)(sg + j0g))[t];  // 1024 floats
  for (int k = t; k < 64 * 32; k += 256) {
    int row = k >> 5, w = k & 31;
    ab[row][w] =
        abits[((size_t)b * Ndim + i0g + row) * (Ndim / 32) + (j0g >> 5) + w];
  }
  const int irow = wv * 16 + li;

  // staging source: wave wv stages u-tile m=wv; lane (q,li) supplies
  // pT[(wv*16+li)*N + j0g + js + q*8 .. +8] (16B)
  const unsigned short* bsrc_h =
      pTh + hb * (size_t)(Udim * Ndim) + (size_t)(wv * 16 + li) * Ndim + j0g +
      q * 8;
  const unsigned short* bsrc_l =
      pTl + hb * (size_t)(Udim * Ndim) + (size_t)(wv * 16 + li) * Ndim + j0g +
      q * 8;

  // stage step 0 into buf 0
  stage16(bsrc_h, &Bst[0][wv * 2 + 0][0]);
  stage16(bsrc_l, &Bst[0][wv * 2 + 1][0]);

  f32x4 acc[4] = {};
  float zacc = 0.f;
  __syncthreads();  // drains vmcnt: sj, ab, staged B all visible

  const float si = sg[i0g + irow];
  int buf = 0;

  for (int js = 0; js < JCHUNK; js += 32) {
    // ---- stage next step into other buffer (async, drained at barrier) ----
    if (js + 32 < JCHUNK) {
      stage16(bsrc_h + js + 32, &Bst[buf ^ 1][wv * 2 + 0][0]);
      stage16(bsrc_l + js + 32, &Bst[buf ^ 1][wv * 2 + 1][0]);
    }
    // ---- B fragments from LDS (lane-linear, conflict-free b128) ----
    const short8 b0h = *(const short8*)&Bst[buf][0][lane * 8];
    const short8 b0l = *(const short8*)&Bst[buf][1][lane * 8];
    const short8 b1h = *(const short8*)&Bst[buf][2][lane * 8];
    const short8 b1l = *(const short8*)&Bst[buf][3][lane * 8];
    const short8 b2h = *(const short8*)&Bst[buf][4][lane * 8];
    const short8 b2l = *(const short8*)&Bst[buf][5][lane * 8];
    const short8 b3h = *(const short8*)&Bst[buf][6][lane * 8];
    const short8 b3l = *(const short8*)&Bst[buf][7][lane * 8];
    // ---- A production: 8 masked exps + hi/lo split, in registers ----
    const unsigned int mb = (ab[irow][js >> 5] >> (q * 8)) & 0xffu;
    const f32x4 s0 = *(const f32x4*)&sj[js + q * 8];
    const f32x4 s1 = *(const f32x4*)&sj[js + q * 8 + 4];
    const float sv[8] = {s0.x, s0.y, s0.z, s0.w, s1.x, s1.y, s1.z, s1.w};
    short8 ahi, alo;
#pragma unroll
    for (int e = 0; e < 8; ++e) {
      float we = __expf(si * sv[e]);
      we = ((mb >> e) & 1u) ? we : 0.f;
      zacc += we;
      unsigned short hh = f2bf_u(we);
      ahi[e] = (short)hh;
      alo[e] = (short)f2bf_u(we - bf2f(hh));
    }
    // ---- 3-product split-bf16 MFMA ----
    acc[0] = __builtin_amdgcn_mfma_f32_16x16x32_bf16(ahi, b0h, acc[0], 0, 0, 0);
    acc[1] = __builtin_amdgcn_mfma_f32_16x16x32_bf16(ahi, b1h, acc[1], 0, 0, 0);
    acc[2] = __builtin_amdgcn_mfma_f32_16x16x32_bf16(ahi, b2h, acc[2], 0, 0, 0);
    acc[3] = __builtin_amdgcn_mfma_f32_16x16x32_bf16(ahi, b3h, acc[3], 0, 0, 0);
    acc[0] = __builtin_amdgcn_mfma_f32_16x16x32_bf16(alo, b0h, acc[0], 0, 0, 0);
    acc[1] = __builtin_amdgcn_mfma_f32_16x16x32_bf16(alo, b1h, acc[1], 0, 0, 0);
    acc[2] = __builtin_amdgcn_mfma_f32_16x16x32_bf16(alo, b2h, acc[2], 0, 0, 0);
    acc[3] = __builtin_amdgcn_mfma_f32_16x16x32_bf16(alo, b3h, acc[3], 0, 0, 0);
    acc[0] = __builtin_amdgcn_mfma_f32_16x16x32_bf16(ahi, b0l, acc[0], 0, 0, 0);
    acc[1] = __builtin_amdgcn_mfma_f32_16x16x32_bf16(ahi, b1l, acc[1], 0, 0, 0);
    acc[2] = __builtin_amdgcn_mfma_f32_16x16x32_bf16(ahi, b2l, acc[2], 0, 0, 0);
    acc[3] = __builtin_amdgcn_mfma_f32_16x16x32_bf16(ahi, b3l, acc[3], 0, 0, 0);
    __syncthreads();  // all waves done with buf; next-step stage landed
    buf ^= 1;
  }

  zl[wv][q][li] = zacc;
  __syncthreads();

  const size_t pslab = ((size_t)h * JC + jc) * Bdim + b;
  if (q == 0) {
    float z = zl[wv][0][li] + zl[wv][1][li] + zl[wv][2][li] + zl[wv][3][li];
    Z_part[pslab * Ndim + i0g + wv * 16 + li] = z;
  }
  float* op = out_part + (pslab * Ndim + i0g + wv * 16) * Udim;
#pragma unroll
  for (int r = 0; r < 4; ++r) {
    const int ir = q * 4 + r;
#pragma unroll
    for (int m = 0; m < 4; ++m) {
      op[(size_t)ir * Udim + m * 16 + li] = acc[m][r];
    }
  }
}

// ---------------- k3: combine partials, normalize, head-mean ----------------
__global__ __launch_bounds__(256) void combine_kernel(
    const float* __restrict__ out_part, const float* __restrict__ Z_part,
    float* __restrict__ out) {
  const int idx = blockIdx.x * 256 + threadIdx.x;
  const int u4 = idx & 15;
  const size_t bn = (size_t)(idx >> 4);
  float4 r = {0.f, 0.f, 0.f, 0.f};
#pragma unroll
  for (int h = 0; h < Hdim; ++h) {
    const size_t s0 = ((size_t)h * JC + 0) * (Bdim * Ndim) + bn;
    const size_t s1 = ((size_t)h * JC + 1) * (Bdim * Ndim) + bn;
    float4 p0 = ((const float4*)out_part)[s0 * (Udim / 4) + u4];
    float4 p1 = ((const float4*)out_part)[s1 * (Udim / 4) + u4];
    float z = Z_part[s0] + Z_part[s1];
    z = (z != 0.f) ? z : 1.f;
    const float inv = 1.f / z;
    r.x += (p0.x + p1.x) * inv;
    r.y += (p0.y + p1.y) * inv;
    r.z += (p0.z + p1.z) * inv;
    r.w += (p0.w + p1.w) * inv;
  }
  r.x *= 0.25f; r.y *= 0.25f; r.z *= 0.25f; r.w *= 0.25f;
  ((float4*)out)[idx] = r;
}

extern "C" void kernel_launch(void* const* d_in, const int* in_sizes, int n_in,
                              void* d_out, int out_size, void* d_ws,
                              size_t ws_size, hipStream_t stream) {
  const float* x = (const float*)d_in[0];
  const int* adj = (const int*)d_in[1];
  const float* W = (const float*)d_in[2];
  const float* bias = (const float*)d_in[3];
  const float* a_w = (const float*)d_in[4];
  const float* a_b = (const float*)d_in[5];
  float* out = (float*)d_out;

  char* ws = (char*)d_ws;
  unsigned short* pTh = (unsigned short*)(ws + 0);
  unsigned short* pTl = (unsigned short*)(ws + 4194304);
  float* s = (float*)(ws + 8388608);
  unsigned int* adjbits = (unsigned int*)(ws + 8519680);
  float* out_part = (float*)(ws + 10616832);
  float* Z_part = (float*)(ws + 27394048);

  const int nchunks = Bdim * Ndim * Ndim / 64;  // 262144
  pack_adj_kernel<<<2048, 256, 0, stream>>>(adj, (unsigned long long*)adjbits,
                                            nchunks);
  proj_kernel<<<Hdim * Bdim * 32, 256, 0, stream>>>(x, W, bias, a_w, a_b, pTh,
                                                    pTl, s);
  attn_mfma_kernel<<<Hdim * Bdim * 32 * JC, 256, 0, stream>>>(
      pTh, pTl, s, adjbits, out_part, Z_part);
  combine_kernel<<<(Bdim * Ndim * Udim / 4) / 256, 256, 0, stream>>>(
      out_part, Z_part, out);
}

// Round 5
// 166.422 us; speedup vs baseline: 2.2734x; 1.0204x over previous
//
#include <hip/hip_runtime.h>
#include <hip/hip_bf16.h>

// GAT layer: B=4, N=2048, F=128, U=64, H=4.
//  k0: pack adj (64MB int32) -> bitmask (2MB)
//  k1: proj GEMM (vector fp32) -> pT_hi/pT_lo bf16 [h][b][u][n] (split fp32),
//      transposed through LDS for coalesced 16B stores; plus s[h][b][n] f32
//  k2: MFMA attention, LDS-staged B (double-buffered global_load_lds,
//      fragment-linear layout), w=adj?exp(si*sj):0 in-register, split bf16
//      via native casts (compiler emits cvt_pk); 3-product split-bf16 MFMA
//      (err ~2^-17). D layout per verified m89.
//  k3: combine: out = 0.25 * sum_h (P0+P1)/(Z0+Z1)
//
// d_ws layout (bytes):
//   pT_hi    @ 0          : H*B*U*N bf16 = 4,194,304
//   pT_lo    @ 4,194,304  : H*B*U*N bf16 = 4,194,304
//   s        @ 8,388,608  : H*B*N   f32  =   131,072
//   adjbits  @ 8,519,680  : B*N*N/8      = 2,097,152
//   out_part @ 10,616,832 : H*JC*B*N*U f32 = 16,777,216
//   Z_part   @ 27,394,048 : H*JC*B*N f32 = 262,144

#define Bdim 4
#define Ndim 2048
#define Fdim 128
#define Udim 64
#define Hdim 4
#define JC 2
#define JCHUNK (Ndim / JC)  // 1024

typedef __attribute__((ext_vector_type(8))) short short8;
typedef __attribute__((ext_vector_type(4))) float f32x4;

// native-cast split: hi = bf16(f) RNE, lo = bf16(f - float(hi))
__device__ __forceinline__ void splitbf(float f, short& hi, short& lo) {
  union { __hip_bfloat16 b; unsigned short u; } ch, cl;
  ch.b = __float2bfloat16(f);
  cl.b = __float2bfloat16(f - __bfloat162float(ch.b));
  hi = (short)ch.u;
  lo = (short)cl.u;
}

// async global->LDS, 16B per lane; dest = wave-uniform base + lane*16
__device__ __forceinline__ void stage16(const void* g, void* l) {
  __builtin_amdgcn_global_load_lds(
      (const __attribute__((address_space(1))) unsigned int*)g,
      (__attribute__((address_space(3))) unsigned int*)l, 16, 0, 0);
}

// ---------------- k0: pack adjacency to bitmask ----------------
__global__ __launch_bounds__(256) void pack_adj_kernel(
    const int* __restrict__ adj, unsigned long long* __restrict__ bits,
    int nchunks) {
  const int lane = threadIdx.x & 63;
  const int wid = (blockIdx.x * 256 + threadIdx.x) >> 6;
  const int nw = (gridDim.x * 256) >> 6;
  for (int c = wid * 4; c + 3 < nchunks; c += nw * 4) {
    int v0 = adj[(size_t)(c + 0) * 64 + lane];
    int v1 = adj[(size_t)(c + 1) * 64 + lane];
    int v2 = adj[(size_t)(c + 2) * 64 + lane];
    int v3 = adj[(size_t)(c + 3) * 64 + lane];
    unsigned long long m0 = __ballot(v0 != 0);
    unsigned long long m1 = __ballot(v1 != 0);
    unsigned long long m2 = __ballot(v2 != 0);
    unsigned long long m3 = __ballot(v3 != 0);
    if (lane == 0) {
      bits[c + 0] = m0;
      bits[c + 1] = m1;
      bits[c + 2] = m2;
      bits[c + 3] = m3;
    }
  }
}

// ---------------- k1: projection -> split-bf16 transposed + s ----------------
// grid: 512 blocks = (h:4, b:4, ntile:32), 256 threads. 64 rows x 64 u.
// pt (LDS transpose buffer) aliases xl (dead after FMA) -> 71KB total.
__global__ __launch_bounds__(256) void proj_kernel(
    const float* __restrict__ x, const float* __restrict__ W,
    const float* __restrict__ bias, const float* __restrict__ a_w,
    const float* __restrict__ a_b, unsigned short* __restrict__ pTh,
    unsigned short* __restrict__ pTl, float* __restrict__ s) {
  const int bid = blockIdx.x;
  const int nt = bid & 31;
  const int b = (bid >> 5) & 3;
  const int h = bid >> 7;
  const int n0 = nt * 64;

  __shared__ __align__(16) char smem[71168];
  float (*Wl)[Udim] = (float(*)[Udim])(smem);              // 32768 B
  float (*xl)[Fdim + 4] = (float(*)[Fdim + 4])(smem + 32768);  // 33792 B
  float (*pt)[68] = (float(*)[68])(smem + 32768);          // alias xl, 17408 B
  float* bl = (float*)(smem + 66560);
  float* awl = (float*)(smem + 66816);
  float (*sred)[16] = (float(*)[16])(smem + 67072);        // 4096 B

  const int t = threadIdx.x;

  const float* Wg = W + (size_t)h * Fdim * Udim;
  for (int k = t; k < Fdim * Udim / 4; k += 256) {
    ((float4*)&Wl[0][0])[k] = ((const float4*)Wg)[k];
  }
  if (t < Udim) {
    bl[t] = bias[h * Udim + t];
    awl[t] = a_w[h * Udim + t];
  }
  const float* xg = x + ((size_t)b * Ndim + n0) * Fdim;
  for (int k = t; k < 64 * Fdim / 4; k += 256) {
    int row = k >> 5;
    int c4 = k & 31;
    float4 v = ((const float4*)xg)[(size_t)row * (Fdim / 4) + c4];
    *(float4*)&xl[row][c4 * 4] = v;
  }
  __syncthreads();

  const int ug = t & 15, rg = t >> 4;
  const int u0 = ug * 4, r0 = rg * 4;
  float acc[4][4] = {};

#pragma unroll 4
  for (int f = 0; f < Fdim; ++f) {
    const float4 wv = *(const float4*)&Wl[f][u0];
    const float xv[4] = {xl[r0][f], xl[r0 + 1][f], xl[r0 + 2][f], xl[r0 + 3][f]};
#pragma unroll
    for (int c = 0; c < 4; ++c) {
      acc[c][0] = fmaf(xv[c], wv.x, acc[c][0]);
      acc[c][1] = fmaf(xv[c], wv.y, acc[c][1]);
      acc[c][2] = fmaf(xv[c], wv.z, acc[c][2]);
      acc[c][3] = fmaf(xv[c], wv.w, acc[c][3]);
    }
  }

  float po[4][4];  // [c = n-offset][k = u-offset]
#pragma unroll
  for (int c = 0; c < 4; ++c)
#pragma unroll
    for (int k = 0; k < 4; ++k)
      po[c][k] = fmaxf(acc[c][k] + bl[u0 + k], 0.f);

#pragma unroll
  for (int c = 0; c < 4; ++c) {
    float sp = po[c][0] * awl[u0 + 0] + po[c][1] * awl[u0 + 1] +
               po[c][2] * awl[u0 + 2] + po[c][3] * awl[u0 + 3];
    sred[r0 + c][ug] = sp;
  }
  __syncthreads();  // all xl reads done; safe to overwrite via pt alias

  // transpose to pt[u][n]
#pragma unroll
  for (int k = 0; k < 4; ++k) {
    float4 v = {po[0][k], po[1][k], po[2][k], po[3][k]};
    *(float4*)&pt[u0 + k][r0] = v;
  }
  __syncthreads();

  // coalesced split-bf16 stores: thread t -> u = t>>2, n-block = (t&3)*16
  const size_t hb = (size_t)h * Bdim + b;
  const int su = t >> 2;
  const int snl = (t & 3) * 16;
  float v[16];
#pragma unroll
  for (int j = 0; j < 4; ++j)
    *(float4*)&v[4 * j] = *(const float4*)&pt[su][snl + 4 * j];
  short hi[16], lo[16];
#pragma unroll
  for (int k = 0; k < 16; ++k) splitbf(v[k], hi[k], lo[k]);
  unsigned short* ph =
      pTh + hb * (size_t)(Udim * Ndim) + (size_t)su * Ndim + n0 + snl;
  unsigned short* pl =
      pTl + hb * (size_t)(Udim * Ndim) + (size_t)su * Ndim + n0 + snl;
  *(short8*)(ph + 0) = *(short8*)&hi[0];
  *(short8*)(ph + 8) = *(short8*)&hi[8];
  *(short8*)(pl + 0) = *(short8*)&lo[0];
  *(short8*)(pl + 8) = *(short8*)&lo[8];

  if (t < 64) {
    float sum = a_b[h];
#pragma unroll
    for (int k = 0; k < 16; ++k) sum += sred[t][k];
    s[hb * Ndim + n0 + t] = sum;
  }
}

// ---------------- k2: MFMA masked-softmax aggregation, LDS-staged B --------
// grid: 1024 blocks = (h:4, b:4, itile:32, jc:2), 256 threads (4 waves).
__global__ __launch_bounds__(256, 4) void attn_mfma_kernel(
    const unsigned short* __restrict__ pTh,
    const unsigned short* __restrict__ pTl, const float* __restrict__ s,
    const unsigned int* __restrict__ abits, float* __restrict__ out_part,
    float* __restrict__ Z_part) {
  const int bid = blockIdx.x;
  const int jc = bid & 1;
  const int it = (bid >> 1) & 31;
  const int b = (bid >> 6) & 3;
  const int h = bid >> 8;
  const int i0g = it * 64;
  const int j0g = jc * JCHUNK;

  __shared__ float sj[JCHUNK];         // 4 KB
  __shared__ unsigned int ab[64][33];  // 8.25 KB padded
  __shared__ short Bst[2][8][512];     // 16 KB: [buf][m*2+hl][lane*8]
  __shared__ float zl[4][4][16];       // 1 KB

  const int t = threadIdx.x;
  const int wv = t >> 6;
  const int lane = t & 63;
  const int q = lane >> 4;
  const int li = lane & 15;
  const size_t hb = (size_t)h * Bdim + b;
  const float* sg = s + hb * Ndim;

  ((float4*)sj)[t] = ((const float4*)(sg + j0g))[t];  // 1024 floats
  for (int k = t; k < 64 * 32; k += 256) {
    int row = k >> 5, w = k & 31;
    ab[row][w] =
        abits[((size_t)b * Ndim + i0g + row) * (Ndim / 32) + (j0g >> 5) + w];
  }
  const int irow = wv * 16 + li;

  const unsigned short* bsrc_h =
      pTh + hb * (size_t)(Udim * Ndim) + (size_t)(wv * 16 + li) * Ndim + j0g +
      q * 8;
  const unsigned short* bsrc_l =
      pTl + hb * (size_t)(Udim * Ndim) + (size_t)(wv * 16 + li) * Ndim + j0g +
      q * 8;

  stage16(bsrc_h, &Bst[0][wv * 2 + 0][0]);
  stage16(bsrc_l, &Bst[0][wv * 2 + 1][0]);

  f32x4 acc[4] = {};
  float zacc = 0.f;
  __syncthreads();  // drains vmcnt: sj, ab, staged B all visible

  const float si = sg[i0g + irow];
  int buf = 0;

  for (int js = 0; js < JCHUNK; js += 32) {
    if (js + 32 < JCHUNK) {
      stage16(bsrc_h + js + 32, &Bst[buf ^ 1][wv * 2 + 0][0]);
      stage16(bsrc_l + js + 32, &Bst[buf ^ 1][wv * 2 + 1][0]);
    }
    const short8 b0h = *(const short8*)&Bst[buf][0][lane * 8];
    const short8 b0l = *(const short8*)&Bst[buf][1][lane * 8];
    const short8 b1h = *(const short8*)&Bst[buf][2][lane * 8];
    const short8 b1l = *(const short8*)&Bst[buf][3][lane * 8];
    const short8 b2h = *(const short8*)&Bst[buf][4][lane * 8];
    const short8 b2l = *(const short8*)&Bst[buf][5][lane * 8];
    const short8 b3h = *(const short8*)&Bst[buf][6][lane * 8];
    const short8 b3l = *(const short8*)&Bst[buf][7][lane * 8];
    const unsigned int mb = (ab[irow][js >> 5] >> (q * 8)) & 0xffu;
    const f32x4 s0 = *(const f32x4*)&sj[js + q * 8];
    const f32x4 s1 = *(const f32x4*)&sj[js + q * 8 + 4];
    const float sv[8] = {s0.x, s0.y, s0.z, s0.w, s1.x, s1.y, s1.z, s1.w};
    short8 ahi, alo;
#pragma unroll
    for (int e = 0; e < 8; ++e) {
      float we = __expf(si * sv[e]);
      we = ((mb >> e) & 1u) ? we : 0.f;
      zacc += we;
      short hh, ll;
      splitbf(we, hh, ll);
      ahi[e] = hh;
      alo[e] = ll;
    }
    acc[0] = __builtin_amdgcn_mfma_f32_16x16x32_bf16(ahi, b0h, acc[0], 0, 0, 0);
    acc[1] = __builtin_amdgcn_mfma_f32_16x16x32_bf16(ahi, b1h, acc[1], 0, 0, 0);
    acc[2] = __builtin_amdgcn_mfma_f32_16x16x32_bf16(ahi, b2h, acc[2], 0, 0, 0);
    acc[3] = __builtin_amdgcn_mfma_f32_16x16x32_bf16(ahi, b3h, acc[3], 0, 0, 0);
    acc[0] = __builtin_amdgcn_mfma_f32_16x16x32_bf16(alo, b0h, acc[0], 0, 0, 0);
    acc[1] = __builtin_amdgcn_mfma_f32_16x16x32_bf16(alo, b1h, acc[1], 0, 0, 0);
    acc[2] = __builtin_amdgcn_mfma_f32_16x16x32_bf16(alo, b2h, acc[2], 0, 0, 0);
    acc[3] = __builtin_amdgcn_mfma_f32_16x16x32_bf16(alo, b3h, acc[3], 0, 0, 0);
    acc[0] = __builtin_amdgcn_mfma_f32_16x16x32_bf16(ahi, b0l, acc[0], 0, 0, 0);
    acc[1] = __builtin_amdgcn_mfma_f32_16x16x32_bf16(ahi, b1l, acc[1], 0, 0, 0);
    acc[2] = __builtin_amdgcn_mfma_f32_16x16x32_bf16(ahi, b2l, acc[2], 0, 0, 0);
    acc[3] = __builtin_amdgcn_mfma_f32_16x16x32_bf16(ahi, b3l, acc[3], 0, 0, 0);
    __syncthreads();
    buf ^= 1;
  }

  zl[wv][q][li] = zacc;
  __syncthreads();

  const size_t pslab = ((size_t)h * JC + jc) * Bdim + b;
  if (q == 0) {
    float z = zl[wv][0][li] + zl[wv][1][li] + zl[wv][2][li] + zl[wv][3][li];
    Z_part[pslab * Ndim + i0g + wv * 16 + li] = z;
  }
  float* op = out_part + (pslab * Ndim + i0g + wv * 16) * Udim;
#pragma unroll
  for (int r = 0; r < 4; ++r) {
    const int ir = q * 4 + r;
#pragma unroll
    for (int m = 0; m < 4; ++m) {
      op[(size_t)ir * Udim + m * 16 + li] = acc[m][r];
    }
  }
}

// ---------------- k3: combine partials, normalize, head-mean ----------------
__global__ __launch_bounds__(256) void combine_kernel(
    const float* __restrict__ out_part, const float* __restrict__ Z_part,
    float* __restrict__ out) {
  const int idx = blockIdx.x * 256 + threadIdx.x;
  const int u4 = idx & 15;
  const size_t bn = (size_t)(idx >> 4);
  float4 r = {0.f, 0.f, 0.f, 0.f};
#pragma unroll
  for (int h = 0; h < Hdim; ++h) {
    const size_t s0 = ((size_t)h * JC + 0) * (Bdim * Ndim) + bn;
    const size_t s1 = ((size_t)h * JC + 1) * (Bdim * Ndim) + bn;
    float4 p0 = ((const float4*)out_part)[s0 * (Udim / 4) + u4];
    float4 p1 = ((const float4*)out_part)[s1 * (Udim / 4) + u4];
    float z = Z_part[s0] + Z_part[s1];
    z = (z != 0.f) ? z : 1.f;
    const float inv = 1.f / z;
    r.x += (p0.x + p1.x) * inv;
    r.y += (p0.y + p1.y) * inv;
    r.z += (p0.z + p1.z) * inv;
    r.w += (p0.w + p1.w) * inv;
  }
  r.x *= 0.25f; r.y *= 0.25f; r.z *= 0.25f; r.w *= 0.25f;
  ((float4*)out)[idx] = r;
}

extern "C" void kernel_launch(void* const* d_in, const int* in_sizes, int n_in,
                              void* d_out, int out_size, void* d_ws,
                              size_t ws_size, hipStream_t stream) {
  const float* x = (const float*)d_in[0];
  const int* adj = (const int*)d_in[1];
  const float* W = (const float*)d_in[2];
  const float* bias = (const float*)d_in[3];
  const float* a_w = (const float*)d_in[4];
  const float* a_b = (const float*)d_in[5];
  float* out = (float*)d_out;

  char* ws = (char*)d_ws;
  unsigned short* pTh = (unsigned short*)(ws + 0);
  unsigned short* pTl = (unsigned short*)(ws + 4194304);
  float* s = (float*)(ws + 8388608);
  unsigned int* adjbits = (unsigned int*)(ws + 8519680);
  float* out_part = (float*)(ws + 10616832);
  float* Z_part = (float*)(ws + 27394048);

  const int nchunks = Bdim * Ndim * Ndim / 64;  // 262144
  pack_adj_kernel<<<2048, 256, 0, stream>>>(adj, (unsigned long long*)adjbits,
                                            nchunks);
  proj_kernel<<<Hdim * Bdim * 32, 256, 0, stream>>>(x, W, bias, a_w, a_b, pTh,
                                                    pTl, s);
  attn_mfma_kernel<<<Hdim * Bdim * 32 * JC, 256, 0, stream>>>(
      pTh, pTl, s, adjbits, out_part, Z_part);
  combine_kernel<<<(Bdim * Ndim * Udim / 4) / 256, 256, 0, stream>>>(
      out_part, Z_part, out);
}